// Round 4
// baseline (690.649 us; speedup 1.0000x reference)
//
#include <hip/hip_runtime.h>

// Round-7: phased-direct. Round-3's fused 2-pass kernel FALSIFIED the
// soft-phasing model (no cross-block sync -> blocks drift across levels ->
// FETCH 1.14GB/pass vs 287MB compulsory floor -> 605us). Restoring the PROVEN
// hard phasing (level = slow blockIdx index: level l+1 blocks only dispatch as
// level-l blocks retire; round-0 measured FETCH=287MB=floor), but keeping
// round-3's structural win: NO ws, NO transpose kernel. Each level's float2
// result is stored directly to out[p*32 + 2*level] as a PLAIN store; the
// per-phase out-partial working set is 1MB/XCD (co-resident in L2 with the
// 4MB hot table), L2 merges the 8 half-row writes, IC merges evicted partials.
// Store line-touches rise 8->64 per wave-store, ~+11% request load on the
// gather-request-bound loop; in exchange the 256MB ws round-trip and kernel B
// (~176us structural) are deleted.

#define TSIZE (1u << 19)
#define HMASK (TSIZE - 1u)
#define P1 2654435761u
#define P2 805459861u

typedef float f32x2 __attribute__((ext_vector_type(2)));

__constant__ float RES_C[16] = {16.f, 20.f, 25.f, 32.f, 40.f, 50.f, 64.f, 80.f,
                                101.f, 128.f, 161.f, 203.f, 256.f, 322.f, 406.f, 512.f};

// ---------------- one level per block, 2 points per thread, direct store ----------------
__global__ __launch_bounds__(256) void gather_direct_kernel(
    const float* __restrict__ x,
    const float* __restrict__ tables,
    float* __restrict__ out,         // [npoints][32]
    int npoints, int levelShift)
{
    const int level = blockIdx.x >> levelShift;              // slow index -> phases
    const int chunk = blockIdx.x & ((1 << levelShift) - 1);
    const float halfr = 0.5f * RES_C[level];                 // 1/grid, exact

    const float2* __restrict__ tab = (const float2*)tables + (size_t)level * TSIZE;

#pragma unroll
    for (int q = 0; q < 2; ++q) {
        const int p = chunk * 512 + q * 256 + threadIdx.x;
        if (p >= npoints) break;

        const float fx = (x[3 * p + 0] + 1.0f) * halfr;
        const float fy = (x[3 * p + 1] + 1.0f) * halfr;
        const float fz = (x[3 * p + 2] + 1.0f) * halfr;

        const float bx = floorf(fx);
        const float by = floorf(fy);
        const float bz = floorf(fz);

        const float wx = fx - bx;
        const float wy = fy - by;
        const float wz = fz - bz;

        const unsigned ix0 = (unsigned)(int)bx;              // * prime 1
        const unsigned iy0 = (unsigned)(int)by * P1;
        const unsigned iz0 = (unsigned)(int)bz * P2;
        const unsigned ix1 = ix0 + 1u;
        const unsigned iy1 = iy0 + P1;
        const unsigned iz1 = iz0 + P2;

        const float2 v000 = tab[(ix0 ^ iy0 ^ iz0) & HMASK];
        const float2 v001 = tab[(ix0 ^ iy0 ^ iz1) & HMASK];
        const float2 v010 = tab[(ix0 ^ iy1 ^ iz0) & HMASK];
        const float2 v011 = tab[(ix0 ^ iy1 ^ iz1) & HMASK];
        const float2 v100 = tab[(ix1 ^ iy0 ^ iz0) & HMASK];
        const float2 v101 = tab[(ix1 ^ iy0 ^ iz1) & HMASK];
        const float2 v110 = tab[(ix1 ^ iy1 ^ iz0) & HMASK];
        const float2 v111 = tab[(ix1 ^ iy1 ^ iz1) & HMASK];

        const float c00a = v000.x + wx * (v100.x - v000.x);
        const float c00b = v000.y + wx * (v100.y - v000.y);
        const float c01a = v001.x + wx * (v101.x - v001.x);
        const float c01b = v001.y + wx * (v101.y - v001.y);
        const float c10a = v010.x + wx * (v110.x - v010.x);
        const float c10b = v010.y + wx * (v110.y - v010.y);
        const float c11a = v011.x + wx * (v111.x - v011.x);
        const float c11b = v011.y + wx * (v111.y - v011.y);

        const float c0a = c00a + wy * (c10a - c00a);
        const float c0b = c00b + wy * (c10b - c00b);
        const float c1a = c01a + wy * (c11a - c01a);
        const float c1b = c01b + wy * (c11b - c01b);

        f32x2 r = { c0a + wz * (c1a - c0a), c0b + wz * (c1b - c0b) };
        // PLAIN partial-line store; merges with the other 7 levels of this
        // half-row in L2 (1MB/XCD per phase) then in the memory-side IC.
        *(f32x2*)(out + (size_t)p * 32 + 2 * level) = r;
    }
}

extern "C" void kernel_launch(void* const* d_in, const int* in_sizes, int n_in,
                              void* d_out, int out_size, void* d_ws, size_t ws_size,
                              hipStream_t stream) {
    const float* x      = (const float*)d_in[0];
    const float* tables = (const float*)d_in[1];
    float* out          = (float*)d_out;

    const int npoints = in_sizes[0] / 3;                       // 1048576

    // chunks per level: ceil(npoints/512) rounded up to power of two
    int chunks = (npoints + 511) / 512;
    int levelShift = 0;
    while ((1 << levelShift) < chunks) ++levelShift;

    dim3 block(256);
    dim3 grid(16 << levelShift);
    hipLaunchKernelGGL(gather_direct_kernel, grid, block, 0, stream,
                       x, tables, out, npoints, levelShift);
}

// Round 5
// 496.536 us; speedup vs baseline: 1.3909x; 1.3909x over previous
//
#include <hip/hip_runtime.h>

// Round-8. R4 falsified direct partial-line stores (WRITE 512MB, FETCH +335MB:
// per-phase out working set is 64MB, not 1MB -> cross-phase RMW thrash).
// Recalibration across R0-R4: bench total = ~140us fixed overhead + kernels;
// B was only ~40us all along, A (~358us) is the target. A is request-bound:
// 128M random 64B-line gathers at ~0.58 lines/cyc/CU (~22.9 TB/s L2-side),
// uniform ~22us/level. This round cuts requests and kills B:
//  - prep:   de-hash levels 0-1 (729+1331 entries, coords limited to
//            [8,16]/[10,20]) into a dense 16.5KB ws copy (one tiny kernel).
//  - K_fine: PROVEN hard-phased gather, but only levels 7-15 (the full-table
//            levels that need phasing) -> ws[9][N] float2, plain stores (IC).
//  - K_final:fused per-point: l0-1 trilinear from LDS (staged coalesced from
//            the dense ws copy), l2-6 global gathers (touched footprints
//            0.17-2.2MB, union 4.4MB ~ one XCD L2 -> drift-immune, no sync
//            needed), l7-15 via 9 coalesced nt stream reads of ws, then
//            full-row LDS transpose -> 2 full 64B lines per point, nt stores.
// LDS = union(dense stage 16.5KB, tile 17.4KB) = 17408B -> 8 blocks/CU.

#define TSIZE (1u << 19)
#define HMASK (TSIZE - 1u)
#define P1 2654435761u
#define P2 805459861u

typedef float f32x4 __attribute__((ext_vector_type(4)));
typedef float f32x2 __attribute__((ext_vector_type(2)));

__constant__ float RES_C[16] = {16.f, 20.f, 25.f, 32.f, 40.f, 50.f, 64.f, 80.f,
                                101.f, 128.f, 161.f, 203.f, 256.f, 322.f, 406.f, 512.f};

// dense-copy geometry for levels 0,1 (x in [0,1) -> coords in [res/2, res])
#define L0_LO 8
#define L0_DIM 9            // 729 entries
#define L1_LO 10
#define L1_DIM 11           // 1331 entries
#define NDENSE (729 + 1331) // 2060 float2 = 16480 B

__device__ __forceinline__ void gather_lerp(const float2* __restrict__ tab,
                                            const float fx, const float fy, const float fz,
                                            float& ra, float& rb)
{
    const float bx = floorf(fx), by = floorf(fy), bz = floorf(fz);
    const float wx = fx - bx, wy = fy - by, wz = fz - bz;

    const unsigned ix0 = (unsigned)(int)bx;              // * prime 1
    const unsigned iy0 = (unsigned)(int)by * P1;
    const unsigned iz0 = (unsigned)(int)bz * P2;
    const unsigned ix1 = ix0 + 1u, iy1 = iy0 + P1, iz1 = iz0 + P2;

    const float2 v000 = tab[(ix0 ^ iy0 ^ iz0) & HMASK];
    const float2 v001 = tab[(ix0 ^ iy0 ^ iz1) & HMASK];
    const float2 v010 = tab[(ix0 ^ iy1 ^ iz0) & HMASK];
    const float2 v011 = tab[(ix0 ^ iy1 ^ iz1) & HMASK];
    const float2 v100 = tab[(ix1 ^ iy0 ^ iz0) & HMASK];
    const float2 v101 = tab[(ix1 ^ iy0 ^ iz1) & HMASK];
    const float2 v110 = tab[(ix1 ^ iy1 ^ iz0) & HMASK];
    const float2 v111 = tab[(ix1 ^ iy1 ^ iz1) & HMASK];

    const float c00a = v000.x + wx * (v100.x - v000.x);
    const float c00b = v000.y + wx * (v100.y - v000.y);
    const float c01a = v001.x + wx * (v101.x - v001.x);
    const float c01b = v001.y + wx * (v101.y - v001.y);
    const float c10a = v010.x + wx * (v110.x - v010.x);
    const float c10b = v010.y + wx * (v110.y - v010.y);
    const float c11a = v011.x + wx * (v111.x - v011.x);
    const float c11b = v011.y + wx * (v111.y - v011.y);

    const float c0a = c00a + wy * (c10a - c00a);
    const float c0b = c00b + wy * (c10b - c00b);
    const float c1a = c01a + wy * (c11a - c01a);
    const float c1b = c01b + wy * (c11b - c01b);

    ra = c0a + wz * (c1a - c0a);
    rb = c0b + wz * (c1b - c0b);
}

// LDS dense trilinear (levels 0,1): identical math, dense [iz][iy][ix] layout.
__device__ __forceinline__ void dense_lerp(const float2* __restrict__ base,
                                           const int lo, const int d,
                                           const float fx, const float fy, const float fz,
                                           float& ra, float& rb)
{
    const float bx = floorf(fx), by = floorf(fy), bz = floorf(fz);
    const float wx = fx - bx, wy = fy - by, wz = fz - bz;
    const int ix = (int)bx - lo, iy = (int)by - lo, iz = (int)bz - lo;
    const int i000 = (iz * d + iy) * d + ix;

    const float2 v000 = base[i000];
    const float2 v100 = base[i000 + 1];
    const float2 v010 = base[i000 + d];
    const float2 v110 = base[i000 + d + 1];
    const float2 v001 = base[i000 + d * d];
    const float2 v101 = base[i000 + d * d + 1];
    const float2 v011 = base[i000 + d * d + d];
    const float2 v111 = base[i000 + d * d + d + 1];

    const float c00a = v000.x + wx * (v100.x - v000.x);
    const float c00b = v000.y + wx * (v100.y - v000.y);
    const float c01a = v001.x + wx * (v101.x - v001.x);
    const float c01b = v001.y + wx * (v101.y - v001.y);
    const float c10a = v010.x + wx * (v110.x - v010.x);
    const float c10b = v010.y + wx * (v110.y - v010.y);
    const float c11a = v011.x + wx * (v111.x - v011.x);
    const float c11b = v011.y + wx * (v111.y - v011.y);

    const float c0a = c00a + wy * (c10a - c00a);
    const float c0b = c00b + wy * (c10b - c00b);
    const float c1a = c01a + wy * (c11a - c01a);
    const float c1b = c01b + wy * (c11b - c01b);

    ra = c0a + wz * (c1a - c0a);
    rb = c0b + wz * (c1b - c0b);
}

// ---------------- prep: de-hash levels 0-1 into dense ws copy ----------------
__global__ __launch_bounds__(256) void prep_dense_kernel(
    const float* __restrict__ tables, float2* __restrict__ dense)
{
    const int i = blockIdx.x * 256 + threadIdx.x;
    const float2* __restrict__ tab = (const float2*)tables;
    if (i < 729) {
        const int ix = i % 9, iy = (i / 9) % 9, iz = i / 81;
        const unsigned h = ((unsigned)(ix + L0_LO)) ^
                           ((unsigned)(iy + L0_LO) * P1) ^
                           ((unsigned)(iz + L0_LO) * P2);
        dense[i] = tab[h & HMASK];                          // level 0
    } else if (i < NDENSE) {
        const int c = i - 729;
        const int ix = c % 11, iy = (c / 11) % 11, iz = c / 121;
        const unsigned h = ((unsigned)(ix + L1_LO)) ^
                           ((unsigned)(iy + L1_LO) * P1) ^
                           ((unsigned)(iz + L1_LO) * P2);
        dense[i] = tab[(size_t)TSIZE + (h & HMASK)];        // level 1
    }
}

// ---------------- K_fine: hard-phased gather, levels 7..15 -> ws ----------------
__global__ __launch_bounds__(256) void gather_fine_kernel(
    const float* __restrict__ x,
    const float* __restrict__ tables,
    f32x2* __restrict__ ws,          // [9][npoints] float2
    int npoints, int levelShift)
{
    const int level = 7 + (blockIdx.x >> levelShift);        // slow index -> phases
    const int chunk = blockIdx.x & ((1 << levelShift) - 1);
    const float halfr = 0.5f * RES_C[level];

    const float2* __restrict__ tab = (const float2*)tables + (size_t)level * TSIZE;
    f32x2* __restrict__ wrow = ws + (size_t)(level - 7) * npoints;

#pragma unroll
    for (int q = 0; q < 2; ++q) {
        const int p = chunk * 512 + q * 256 + threadIdx.x;
        if (p >= npoints) break;

        const float fx = (x[3 * p + 0] + 1.0f) * halfr;
        const float fy = (x[3 * p + 1] + 1.0f) * halfr;
        const float fz = (x[3 * p + 2] + 1.0f) * halfr;

        float ra, rb;
        gather_lerp(tab, fx, fy, fz, ra, rb);
        f32x2 r = { ra, rb };
        wrow[p] = r;    // plain: L2 -> Infinity Cache (R2's proven win)
    }
}

// ---------------- K_final: l0-1 LDS + l2-6 global + l7-15 ws -> out ----------------
__global__ __launch_bounds__(256) void final_kernel(
    const float* __restrict__ x,
    const float* __restrict__ tables,
    const f32x2* __restrict__ ws,    // [9][npoints] float2
    const float2* __restrict__ dense_ws,
    float* __restrict__ out,
    int npoints)
{
    // union: phase 1 = 2060 float2 dense stage (16480B); phase 2 = 256x17 tile
    __shared__ float smem[4352];     // 17408 B -> 8 blocks/CU

    const int t = threadIdx.x;
    const int base = blockIdx.x * 256;

    // stage dense levels 0-1 (coalesced; source is L2/IC-hot after first blocks)
    {
        float2* sd = (float2*)smem;
        for (int i = t; i < NDENSE; i += 256)
            sd[i] = dense_ws[i];
    }
    __syncthreads();

    if (base + 256 <= npoints) {
        const int p = base + t;
        const float px = x[3 * p + 0] + 1.0f;
        const float py = x[3 * p + 1] + 1.0f;
        const float pz = x[3 * p + 2] + 1.0f;

        float acc[32];
        const float2* __restrict__ sd = (const float2*)smem;

        // levels 0,1 from LDS dense copies
        dense_lerp(sd,       L0_LO, L0_DIM, px * 8.0f,  py * 8.0f,  pz * 8.0f,
                   acc[0], acc[1]);
        dense_lerp(sd + 729, L1_LO, L1_DIM, px * 10.0f, py * 10.0f, pz * 10.0f,
                   acc[2], acc[3]);

        // levels 2..6 global hashed gathers (footprints 0.17-2.2MB, union
        // ~4.4MB ~ one XCD L2 -> soft-phase safe, no sync needed)
#pragma unroll
        for (int l = 2; l < 7; ++l) {
            const float halfr = 0.5f * RES_C[l];
            const float2* __restrict__ tab = (const float2*)tables + (size_t)l * TSIZE;
            gather_lerp(tab, px * halfr, py * halfr, pz * halfr,
                        acc[2 * l], acc[2 * l + 1]);
        }

        // levels 7..15 from ws: 9 coalesced nontemporal stream reads
#pragma unroll
        for (int li = 0; li < 9; ++li) {
            f32x2 v = __builtin_nontemporal_load(ws + (size_t)li * npoints + p);
            acc[14 + 2 * li]     = v.x;
            acc[14 + 2 * li + 1] = v.y;
        }

        __syncthreads();   // done reading sdense; reuse smem as transpose tile

        // ---- line 0: levels 0-7 (floats 0..15 of the out row) ----
#pragma unroll
        for (int i = 0; i < 16; ++i)
            smem[t * 17 + i] = acc[i];
        __syncthreads();
        {
            float* obase = out + (size_t)base * 32;
#pragma unroll
            for (int k = 0; k < 4; ++k) {
                const int s  = k * 256 + t;
                const int pt = s >> 2;
                const int c  = s & 3;
                f32x4 q = { smem[pt * 17 + 4 * c + 0], smem[pt * 17 + 4 * c + 1],
                            smem[pt * 17 + 4 * c + 2], smem[pt * 17 + 4 * c + 3] };
                __builtin_nontemporal_store(q, (f32x4*)(obase + (size_t)pt * 32 + 4 * c));
            }
        }
        __syncthreads();

        // ---- line 1: levels 8-15 (floats 16..31) ----
#pragma unroll
        for (int i = 0; i < 16; ++i)
            smem[t * 17 + i] = acc[16 + i];
        __syncthreads();
        {
            float* obase = out + (size_t)base * 32 + 16;
#pragma unroll
            for (int k = 0; k < 4; ++k) {
                const int s  = k * 256 + t;
                const int pt = s >> 2;
                const int c  = s & 3;
                f32x4 q = { smem[pt * 17 + 4 * c + 0], smem[pt * 17 + 4 * c + 1],
                            smem[pt * 17 + 4 * c + 2], smem[pt * 17 + 4 * c + 3] };
                __builtin_nontemporal_store(q, (f32x4*)(obase + (size_t)pt * 32 + 4 * c));
            }
        }
    } else {
        // tail (not taken at npoints = 2^20; kept for safety)
        const int p = base + t;
        if (p < npoints) {
            const float px = x[3 * p + 0] + 1.0f;
            const float py = x[3 * p + 1] + 1.0f;
            const float pz = x[3 * p + 2] + 1.0f;
            float acc[32];
            const float2* __restrict__ sd = (const float2*)smem;
            dense_lerp(sd,       L0_LO, L0_DIM, px * 8.0f,  py * 8.0f,  pz * 8.0f,
                       acc[0], acc[1]);
            dense_lerp(sd + 729, L1_LO, L1_DIM, px * 10.0f, py * 10.0f, pz * 10.0f,
                       acc[2], acc[3]);
#pragma unroll
            for (int l = 2; l < 7; ++l) {
                const float halfr = 0.5f * RES_C[l];
                const float2* __restrict__ tab = (const float2*)tables + (size_t)l * TSIZE;
                gather_lerp(tab, px * halfr, py * halfr, pz * halfr,
                            acc[2 * l], acc[2 * l + 1]);
            }
#pragma unroll
            for (int li = 0; li < 9; ++li) {
                f32x2 v = ws[(size_t)li * npoints + p];
                acc[14 + 2 * li]     = v.x;
                acc[14 + 2 * li + 1] = v.y;
            }
            float* orow = out + (size_t)p * 32;
#pragma unroll
            for (int i = 0; i < 8; ++i) {
                f32x4 v = { acc[4 * i + 0], acc[4 * i + 1], acc[4 * i + 2], acc[4 * i + 3] };
                *(f32x4*)(orow + 4 * i) = v;
            }
        }
    }
}

// ---------------- Fallback if ws too small (all 16 levels, one pass) ----------------
__global__ __launch_bounds__(256) void hashgrid_fallback_kernel(
    const float* __restrict__ x,
    const float* __restrict__ tables,
    float* __restrict__ out)
{
    const int p = blockIdx.x * 256 + threadIdx.x;

    const float px = x[3 * p + 0] + 1.0f;
    const float py = x[3 * p + 1] + 1.0f;
    const float pz = x[3 * p + 2] + 1.0f;

    float acc[32];
    const float2* __restrict__ tab = (const float2*)tables;

#pragma unroll
    for (int l = 0; l < 16; ++l) {
        const float halfr = 0.5f * RES_C[l];
        float ra, rb;
        gather_lerp(tab + (size_t)l * TSIZE, px * halfr, py * halfr, pz * halfr, ra, rb);
        acc[2 * l + 0] = ra;
        acc[2 * l + 1] = rb;
    }

    f32x4* orow = (f32x4*)(out + (size_t)p * 32);
#pragma unroll
    for (int i = 0; i < 8; ++i) {
        f32x4 v = { acc[4 * i + 0], acc[4 * i + 1], acc[4 * i + 2], acc[4 * i + 3] };
        orow[i] = v;
    }
}

extern "C" void kernel_launch(void* const* d_in, const int* in_sizes, int n_in,
                              void* d_out, int out_size, void* d_ws, size_t ws_size,
                              hipStream_t stream) {
    const float* x      = (const float*)d_in[0];
    const float* tables = (const float*)d_in[1];
    float* out          = (float*)d_out;

    const int npoints = in_sizes[0] / 3;                       // 1048576
    const size_t fine_bytes = (size_t)9 * npoints * sizeof(float2);  // 72 MB
    const size_t ws_needed  = fine_bytes + NDENSE * sizeof(float2);

    if (ws_size >= ws_needed) {
        f32x2*  ws_fine  = (f32x2*)d_ws;
        float2* dense_ws = (float2*)((char*)d_ws + fine_bytes);

        hipLaunchKernelGGL(prep_dense_kernel, dim3((NDENSE + 255) / 256), dim3(256),
                           0, stream, tables, dense_ws);

        int chunks = (npoints + 511) / 512;
        int levelShift = 0;
        while ((1 << levelShift) < chunks) ++levelShift;
        hipLaunchKernelGGL(gather_fine_kernel, dim3(9 << levelShift), dim3(256),
                           0, stream, x, tables, ws_fine, npoints, levelShift);

        hipLaunchKernelGGL(final_kernel, dim3((npoints + 255) / 256), dim3(256),
                           0, stream, x, tables, ws_fine, dense_ws, out, npoints);
    } else {
        hipLaunchKernelGGL(hashgrid_fallback_kernel, dim3((npoints + 255) / 256),
                           dim3(256), 0, stream, x, tables, out);
    }
}